// Round 1
// baseline (383.811 us; speedup 1.0000x reference)
//
#include <hip/hip_runtime.h>
#include <math.h>

#define TS 32
#define HALO 10
#define IN_TS (TS + HALO)   // 42

struct GaussW { float g[11]; };

__global__ void init_acc_kernel(float* acc) {
    int i = threadIdx.x;
    if (i < 128) acc[i] = 0.f;
}

__global__ __launch_bounds__(256) void ssim_level_kernel(
    const float* __restrict__ X, const float* __restrict__ Y,
    int H, int W, GaussW gw,
    float* __restrict__ cs_sum, float* __restrict__ ss_sum)
{
    __shared__ float Xs[IN_TS][IN_TS + 1];
    __shared__ float Ys[IN_TS][IN_TS + 1];
    __shared__ float Hx [IN_TS][TS + 1];
    __shared__ float Hy [IN_TS][TS + 1];
    __shared__ float Hxx[IN_TS][TS + 1];
    __shared__ float Hyy[IN_TS][TS + 1];
    __shared__ float Hxy[IN_TS][TS + 1];
    __shared__ float red[8];

    const int tid = threadIdx.x;
    const int bc  = blockIdx.z;          // b*3 + c
    const int b   = bc / 3;
    const int r0  = blockIdx.y * TS;
    const int c0  = blockIdx.x * TS;
    const size_t base = (size_t)bc * H * W;
    const float* Xp = X + base;
    const float* Yp = Y + base;

    // Phase 1: load input tile (with halo), zero-fill out of range
    for (int idx = tid; idx < IN_TS * IN_TS; idx += 256) {
        int rr = idx / IN_TS, cc = idx - rr * IN_TS;
        int gr = r0 + rr, gc = c0 + cc;
        float xv = 0.f, yv = 0.f;
        if (gr < H && gc < W) {
            size_t o = (size_t)gr * W + gc;
            xv = Xp[o];
            yv = Yp[o];
        }
        Xs[rr][cc] = xv;
        Ys[rr][cc] = yv;
    }
    __syncthreads();

    // Phase 2: horizontal 11-tap blur of the 5 quantities
    for (int idx = tid; idx < IN_TS * TS; idx += 256) {
        int rr = idx / TS, cc = idx - rr * TS;
        float gx = 0.f, gy = 0.f, gxx = 0.f, gyy = 0.f, gxy = 0.f;
        #pragma unroll
        for (int k = 0; k < 11; ++k) {
            float w  = gw.g[k];
            float xv = Xs[rr][cc + k];
            float yv = Ys[rr][cc + k];
            gx  += w * xv;
            gy  += w * yv;
            gxx += w * xv * xv;
            gyy += w * yv * yv;
            gxy += w * xv * yv;
        }
        Hx [rr][cc] = gx;  Hy [rr][cc] = gy;
        Hxx[rr][cc] = gxx; Hyy[rr][cc] = gyy; Hxy[rr][cc] = gxy;
    }
    __syncthreads();

    // Phase 3: vertical blur + SSIM math + per-thread accumulate
    const int Hout = H - HALO, Wout = W - HALO;
    const int tx = tid & 31, ty = tid >> 5;
    const float C1 = 1e-4f, C2 = 9e-4f;
    float cs_acc = 0.f, ss_acc = 0.f;
    for (int rr = ty; rr < TS; rr += 8) {
        int gor = r0 + rr, goc = c0 + tx;
        if (gor < Hout && goc < Wout) {
            float mu1 = 0.f, mu2 = 0.f, s11 = 0.f, s22 = 0.f, s12 = 0.f;
            #pragma unroll
            for (int k = 0; k < 11; ++k) {
                float w = gw.g[k];
                mu1 += w * Hx [rr + k][tx];
                mu2 += w * Hy [rr + k][tx];
                s11 += w * Hxx[rr + k][tx];
                s22 += w * Hyy[rr + k][tx];
                s12 += w * Hxy[rr + k][tx];
            }
            float v1  = s11 - mu1 * mu1;
            float v2  = s22 - mu2 * mu2;
            float v12 = s12 - mu1 * mu2;
            float cs  = fmaxf((2.f * v12 + C2) / (v1 + v2 + C2), 0.f);
            float ss  = (2.f * mu1 * mu2 + C1) / (mu1 * mu1 + mu2 * mu2 + C1) * cs;
            cs_acc += cs;
            ss_acc += ss;
        }
    }

    // Phase 4: block reduction (wave shuffle, then cross-wave via LDS)
    #pragma unroll
    for (int off = 32; off > 0; off >>= 1) {
        cs_acc += __shfl_down(cs_acc, off);
        ss_acc += __shfl_down(ss_acc, off);
    }
    if ((tid & 63) == 0) {
        int wid = tid >> 6;
        red[wid]     = cs_acc;
        red[4 + wid] = ss_acc;
    }
    __syncthreads();
    if (tid == 0) {
        atomicAdd(&cs_sum[b], red[0] + red[1] + red[2] + red[3]);
        atomicAdd(&ss_sum[b], red[4] + red[5] + red[6] + red[7]);
    }
}

__global__ __launch_bounds__(256) void pool2_kernel(
    const float* __restrict__ in, float* __restrict__ out,
    int Hin, int Win, int n_out)
{
    int i = blockIdx.x * blockDim.x + threadIdx.x;
    if (i >= n_out) return;
    int Wout = Win >> 1, Houtp = Hin >> 1;
    int c  = i % Wout;
    int t  = i / Wout;
    int r  = t % Houtp;
    int bc = t / Houtp;
    const float* p = in + (size_t)bc * Hin * Win + (size_t)(2 * r) * Win + 2 * c;
    out[i] = 0.25f * (p[0] + p[1] + p[Win] + p[Win + 1]);
}

__global__ void finalize_kernel(const float* __restrict__ acc, float* __restrict__ out) {
    int b = threadIdx.x;
    if (b >= 16) return;
    const float wraw[4] = {0.0448f, 0.2856f, 0.3001f, 0.2363f};
    float wsum = wraw[0] + wraw[1] + wraw[2] + wraw[3];
    float ms = 1.f;
    for (int l = 0; l < 4; ++l) {
        int H = 512 >> l;
        int Hout = H - HALO;
        float cnt = 3.f * (float)Hout * (float)Hout;
        float val = (l < 3 ? acc[l * 16 + b] : acc[64 + l * 16 + b]) / cnt;
        val = fmaxf(val, 1e-8f);
        ms *= powf(val, wraw[l] / wsum);
    }
    out[b] = 1.f - ms;
}

extern "C" void kernel_launch(void* const* d_in, const int* in_sizes, int n_in,
                              void* d_out, int out_size, void* d_ws, size_t ws_size,
                              hipStream_t stream)
{
    const float* X0 = (const float*)d_in[0];
    const float* Y0 = (const float*)d_in[1];
    float* out = (float*)d_out;
    float* ws  = (float*)d_ws;

    // ws layout (floats):
    // acc: [4][16] cs sums | [4][16] ss sums  -> 128
    // X1,Y1: 16*3*256*256 each; X2,Y2: 16*3*128*128; X3,Y3: 16*3*64*64
    float* acc = ws;
    float* cs_base = acc;
    float* ss_base = acc + 64;
    float* X1 = ws + 128;
    float* Y1 = X1 + (size_t)16 * 3 * 256 * 256;
    float* X2 = Y1 + (size_t)16 * 3 * 256 * 256;
    float* Y2 = X2 + (size_t)16 * 3 * 128 * 128;
    float* X3 = Y2 + (size_t)16 * 3 * 128 * 128;
    float* Y3 = X3 + (size_t)16 * 3 * 64 * 64;

    GaussW gw;
    {
        float s = 0.f;
        for (int i = 0; i < 11; ++i) {
            float d = (float)(i - 5);
            gw.g[i] = expf(-d * d / (2.f * 1.5f * 1.5f));
            s += gw.g[i];
        }
        for (int i = 0; i < 11; ++i) gw.g[i] /= s;
    }

    hipLaunchKernelGGL(init_acc_kernel, dim3(1), dim3(128), 0, stream, acc);

    const float* Xl[4] = {X0, X1, X2, X3};
    const float* Yl[4] = {Y0, Y1, Y2, Y3};
    float* Xn[3] = {X1, X2, X3};
    float* Yn[3] = {Y1, Y2, Y3};
    const int Hs[4] = {512, 256, 128, 64};

    for (int l = 0; l < 4; ++l) {
        int H = Hs[l];
        int Hout = H - HALO;
        int tiles = (Hout + TS - 1) / TS;
        hipLaunchKernelGGL(ssim_level_kernel, dim3(tiles, tiles, 48), dim3(256), 0, stream,
                           Xl[l], Yl[l], H, H, gw, cs_base + l * 16, ss_base + l * 16);
        if (l < 3) {
            int n = 48 * (H / 2) * (H / 2);
            int grid = (n + 255) / 256;
            hipLaunchKernelGGL(pool2_kernel, dim3(grid), dim3(256), 0, stream, Xl[l], Xn[l], H, H, n);
            hipLaunchKernelGGL(pool2_kernel, dim3(grid), dim3(256), 0, stream, Yl[l], Yn[l], H, H, n);
        }
    }

    hipLaunchKernelGGL(finalize_kernel, dim3(1), dim3(16), 0, stream, acc, out);
}

// Round 2
// 330.827 us; speedup vs baseline: 1.1602x; 1.1602x over previous
//
#include <hip/hip_runtime.h>
#include <math.h>

#define HALO 10
#define TS 32
#define LSTR 46   // LDS row stride: !=0 mod 4 would break b64 align; 8*46%32=16 keeps writes 2-way

struct GaussW { float g[11]; };

__global__ void init_acc_kernel(float* acc) {
    int i = threadIdx.x;
    if (i < 128) acc[i] = 0.f;
}

template <int H, bool DO_POOL>
__global__ __launch_bounds__(256) void ssim_level_kernel(
    const float* __restrict__ X, const float* __restrict__ Y,
    GaussW gw, float* __restrict__ sum_out,
    float* __restrict__ Xpool, float* __restrict__ Ypool)
{
    constexpr int W = H;
    constexpr int Hout = H - HALO;
    constexpr int Wout = W - HALO;

    // Transposed blurred-quantity tiles: [quantity][out_col][in_row]
    __shared__ float Hs[5][TS][LSTR];
    __shared__ float red[4];

    const int tid = threadIdx.x;
    const int bc  = blockIdx.z;        // b*3 + c
    const int b   = bc / 3;
    const int r0  = blockIdx.y * TS;
    const int c0  = blockIdx.x * TS;
    const size_t base = (size_t)bc * H * W;

    // ---- Phase A: horizontal 11-tap blur of {x, y, xx, yy, xy}, direct from global ----
    // 42 rows x 4 segments of 8 output cols = 168 threads
    if (tid < 168) {
        const int rr  = tid >> 2;
        const int seg = tid & 3;
        const int gr  = r0 + rr;
        const int gc0 = c0 + seg * 8;
        const bool rowok = (gr < H);

        float x[20], y[20];
        if (rowok && (gc0 + 20 <= W)) {
            const float* xp = X + base + (size_t)gr * W + gc0;
            const float* yp = Y + base + (size_t)gr * W + gc0;
            #pragma unroll
            for (int v = 0; v < 5; ++v) {
                float4 xv = *(const float4*)(xp + 4 * v);
                float4 yv = *(const float4*)(yp + 4 * v);
                x[4*v+0] = xv.x; x[4*v+1] = xv.y; x[4*v+2] = xv.z; x[4*v+3] = xv.w;
                y[4*v+0] = yv.x; y[4*v+1] = yv.y; y[4*v+2] = yv.z; y[4*v+3] = yv.w;
            }
        } else {
            const int grc = rowok ? gr : (H - 1);
            const float* xp = X + base + (size_t)grc * W;
            const float* yp = Y + base + (size_t)grc * W;
            #pragma unroll
            for (int i = 0; i < 20; ++i) {
                int gc  = gc0 + i;
                int gcc = gc < W ? gc : (W - 1);
                bool ok = rowok && (gc < W);
                float xv = xp[gcc], yv = yp[gcc];
                x[i] = ok ? xv : 0.f;
                y[i] = ok ? yv : 0.f;
            }
        }

        const int ccb = seg * 8;
        // linear terms
        #pragma unroll
        for (int j = 0; j < 8; ++j) {
            float s = 0.f;
            #pragma unroll
            for (int k = 0; k < 11; ++k) s = fmaf(gw.g[k], x[j + k], s);
            Hs[0][ccb + j][rr] = s;
        }
        #pragma unroll
        for (int j = 0; j < 8; ++j) {
            float s = 0.f;
            #pragma unroll
            for (int k = 0; k < 11; ++k) s = fmaf(gw.g[k], y[j + k], s);
            Hs[1][ccb + j][rr] = s;
        }
        // products computed once, then blurred
        float t[18];
        #pragma unroll
        for (int i = 0; i < 18; ++i) t[i] = x[i] * x[i];
        #pragma unroll
        for (int j = 0; j < 8; ++j) {
            float s = 0.f;
            #pragma unroll
            for (int k = 0; k < 11; ++k) s = fmaf(gw.g[k], t[j + k], s);
            Hs[2][ccb + j][rr] = s;
        }
        #pragma unroll
        for (int i = 0; i < 18; ++i) t[i] = y[i] * y[i];
        #pragma unroll
        for (int j = 0; j < 8; ++j) {
            float s = 0.f;
            #pragma unroll
            for (int k = 0; k < 11; ++k) s = fmaf(gw.g[k], t[j + k], s);
            Hs[3][ccb + j][rr] = s;
        }
        #pragma unroll
        for (int i = 0; i < 18; ++i) t[i] = x[i] * y[i];
        #pragma unroll
        for (int j = 0; j < 8; ++j) {
            float s = 0.f;
            #pragma unroll
            for (int k = 0; k < 11; ++k) s = fmaf(gw.g[k], t[j + k], s);
            Hs[4][ccb + j][rr] = s;
        }
    }
    __syncthreads();

    // ---- Phase C: vertical 11-tap blur (b64 contiguous reads) + SSIM math ----
    const int tx = tid & 31;     // output col
    const int ty = tid >> 5;     // 0..7, owns 4 consecutive output rows
    const int rb = ty * 4;

    float m1[4], m2[4], sxx[4], syy[4], sxy[4];
    #define VPASS(Q, OUT)                                                        \
    {                                                                            \
        float win[14];                                                           \
        _Pragma("unroll")                                                        \
        for (int i = 0; i < 7; ++i)                                              \
            *(float2*)&win[2 * i] = *(const float2*)&Hs[Q][tx][rb + 2 * i];      \
        _Pragma("unroll")                                                        \
        for (int o = 0; o < 4; ++o) {                                            \
            float s = 0.f;                                                       \
            _Pragma("unroll")                                                    \
            for (int k = 0; k < 11; ++k) s = fmaf(gw.g[k], win[o + k], s);       \
            OUT[o] = s;                                                          \
        }                                                                        \
    }
    VPASS(0, m1) VPASS(1, m2) VPASS(2, sxx) VPASS(3, syy) VPASS(4, sxy)
    #undef VPASS

    const float C1 = 1e-4f, C2 = 9e-4f;
    float acc_s = 0.f;
    #pragma unroll
    for (int o = 0; o < 4; ++o) {
        float u1 = m1[o], u2 = m2[o];
        float u1s = u1 * u1, u2s = u2 * u2, u12 = u1 * u2;
        float v1  = sxx[o] - u1s;
        float v2  = syy[o] - u2s;
        float v12 = sxy[o] - u12;
        float A2  = fmaxf(2.f * v12 + C2, 0.f);
        float B1  = u1s + u2s + C1;
        float B2  = v1 + v2 + C2;
        float inv = __builtin_amdgcn_rcpf(B1 * B2);
        float val;
        if (DO_POOL) {                 // levels 0-2: need cs = A2/B2
            val = A2 * B1 * inv;
        } else {                       // level 3: need ss = A1/B1 * A2/B2
            float A1 = 2.f * u12 + C1;
            val = A1 * A2 * inv;
        }
        bool valid = (r0 + rb + o < Hout) && (c0 + tx < Wout);
        acc_s += valid ? val : 0.f;
    }

    // ---- Phase D: fused 2x2 avg-pool of this block's 32x32 input region ----
    if (DO_POOL) {
        constexpr int Wp = W / 2;
        const int pr = tid >> 4, pc = tid & 15;
        const size_t srow = base + (size_t)(r0 + 2 * pr) * W + (c0 + 2 * pc);
        float2 xa = *(const float2*)(X + srow);
        float2 xb = *(const float2*)(X + srow + W);
        float2 ya = *(const float2*)(Y + srow);
        float2 yb = *(const float2*)(Y + srow + W);
        const size_t o = (size_t)bc * (H / 2) * Wp + (size_t)(r0 / 2 + pr) * Wp + (c0 / 2 + pc);
        Xpool[o] = 0.25f * (xa.x + xa.y + xb.x + xb.y);
        Ypool[o] = 0.25f * (ya.x + ya.y + yb.x + yb.y);
    }

    // ---- Phase E: block reduction + one atomic ----
    #pragma unroll
    for (int off = 32; off; off >>= 1) acc_s += __shfl_down(acc_s, off);
    if ((tid & 63) == 0) red[tid >> 6] = acc_s;
    __syncthreads();
    if (tid == 0) atomicAdd(&sum_out[b], red[0] + red[1] + red[2] + red[3]);
}

__global__ void finalize_kernel(const float* __restrict__ acc, float* __restrict__ out) {
    int b = threadIdx.x;
    if (b >= 16) return;
    const float wraw[4] = {0.0448f, 0.2856f, 0.3001f, 0.2363f};
    float wsum = wraw[0] + wraw[1] + wraw[2] + wraw[3];
    float ms = 1.f;
    for (int l = 0; l < 4; ++l) {
        int H = 512 >> l;
        int Hout = H - HALO;
        float cnt = 3.f * (float)Hout * (float)Hout;
        float val = (l < 3 ? acc[l * 16 + b] : acc[64 + l * 16 + b]) / cnt;
        val = fmaxf(val, 1e-8f);
        ms *= powf(val, wraw[l] / wsum);
    }
    out[b] = 1.f - ms;
}

extern "C" void kernel_launch(void* const* d_in, const int* in_sizes, int n_in,
                              void* d_out, int out_size, void* d_ws, size_t ws_size,
                              hipStream_t stream)
{
    const float* X0 = (const float*)d_in[0];
    const float* Y0 = (const float*)d_in[1];
    float* out = (float*)d_out;
    float* ws  = (float*)d_ws;

    // ws layout (floats): acc[128] | X1 | Y1 | X2 | Y2 | X3 | Y3
    float* acc = ws;
    float* X1 = ws + 128;
    float* Y1 = X1 + (size_t)16 * 3 * 256 * 256;
    float* X2 = Y1 + (size_t)16 * 3 * 256 * 256;
    float* Y2 = X2 + (size_t)16 * 3 * 128 * 128;
    float* X3 = Y2 + (size_t)16 * 3 * 128 * 128;
    float* Y3 = X3 + (size_t)16 * 3 * 64 * 64;

    GaussW gw;
    {
        float s = 0.f;
        for (int i = 0; i < 11; ++i) {
            float d = (float)(i - 5);
            gw.g[i] = expf(-d * d / (2.f * 1.5f * 1.5f));
            s += gw.g[i];
        }
        for (int i = 0; i < 11; ++i) gw.g[i] /= s;
    }

    hipLaunchKernelGGL(init_acc_kernel, dim3(1), dim3(128), 0, stream, acc);

    // levels 0-2 accumulate cs into acc[l*16 + b]; level 3 accumulates ss into acc[64 + 48 + b]
    hipLaunchKernelGGL((ssim_level_kernel<512, true>),  dim3(16, 16, 48), dim3(256), 0, stream,
                       X0, Y0, gw, acc + 0,   X1, Y1);
    hipLaunchKernelGGL((ssim_level_kernel<256, true>),  dim3(8, 8, 48),   dim3(256), 0, stream,
                       X1, Y1, gw, acc + 16,  X2, Y2);
    hipLaunchKernelGGL((ssim_level_kernel<128, true>),  dim3(4, 4, 48),   dim3(256), 0, stream,
                       X2, Y2, gw, acc + 32,  X3, Y3);
    hipLaunchKernelGGL((ssim_level_kernel<64, false>),  dim3(2, 2, 48),   dim3(256), 0, stream,
                       X3, Y3, gw, acc + 112, (float*)nullptr, (float*)nullptr);

    hipLaunchKernelGGL(finalize_kernel, dim3(1), dim3(16), 0, stream, acc, out);
}